// Round 1
// baseline (400.673 us; speedup 1.0000x reference)
//
#include <hip/hip_runtime.h>
#include <math.h>

#ifndef M_PI
#define M_PI 3.14159265358979323846
#endif

#define NAANG 1152
#define NDET  736
#define NPIX  512
#define PADN  2048
#define NHALF 1025   // PADN/2 + 1

// ---- workspace layout (byte offsets) ----
// double FILT[1025]            @ 0       (8200 B, padded to 8320)
// float  h[2048]               @ 8320    (8192 B)
// float  cosA[1152]            @ 16512   (4608 B)
// float  sinA[1152]            @ 21120   (4608 B)
// float  filtered[1152*736]    @ 25728   (3391488 B)
// total ~3.42 MB
#define OFF_FILTD 0
#define OFF_H     8320
#define OFF_COS   16512
#define OFF_SIN   21120
#define OFF_FS    25728

// ---------------------------------------------------------------------------
// Kernel 1: FILT[m] = Shepp-Logan half-spectrum (double precision).
// four = 2*Re(FFT(f)); f[0]=0.25, f[2j+1] = -1/(pi*n_j)^2 with
// n_j = (j<512) ? 2j+1 : 2047-2j.  Then window sin(w)/w for m>=1.
// One block per m, 256-thread reduction over j.
// ---------------------------------------------------------------------------
__global__ void filt_spec_kernel(double* __restrict__ filt_d) {
    __shared__ double red[256];
    const int m = blockIdx.x;          // 0..1024
    const int t = threadIdx.x;
    double s = 0.0;
    for (int j = t; j < 1024; j += 256) {
        int n = (j < 512) ? (2 * j + 1) : (2047 - 2 * j);
        double fj = -1.0 / ((M_PI * n) * (M_PI * n));
        double ang = (2.0 * M_PI) * (double)m * (double)(2 * j + 1) / (double)PADN;
        s += fj * cos(ang);
    }
    red[t] = s;
    __syncthreads();
    for (int w = 128; w > 0; w >>= 1) {
        if (t < w) red[t] += red[t + w];
        __syncthreads();
    }
    if (t == 0) {
        double four = 2.0 * (0.25 + red[0]);
        if (m > 0) {
            double om = M_PI * (double)m / (double)PADN;
            four *= sin(om) / om;
        }
        filt_d[m] = four;
    }
}

// ---------------------------------------------------------------------------
// Kernel 2: h[k] = irfft(FILT, 2048)[k]  (double precision sum).
// x[k] = (1/N) * ( X0 + 2*sum_{m=1}^{N/2-1} Xm*cos(2pi m k/N) + (-1)^k * X_{N/2} )
// One block per k, 256-thread reduction over m.
// ---------------------------------------------------------------------------
__global__ void h_kernel(const double* __restrict__ filt_d, float* __restrict__ h) {
    __shared__ double red[256];
    const int k = blockIdx.x;          // 0..2047
    const int t = threadIdx.x;
    double s = 0.0;
    for (int m = t; m <= 1024; m += 256) {
        double c;
        if (m == 0) c = 1.0;
        else if (m == 1024) c = (k & 1) ? -1.0 : 1.0;
        else c = 2.0 * cos((2.0 * M_PI) * (double)m * (double)k / (double)PADN);
        s += filt_d[m] * c;
    }
    red[t] = s;
    __syncthreads();
    for (int w = 128; w > 0; w >>= 1) {
        if (t < w) red[t] += red[t + w];
        __syncthreads();
    }
    if (t == 0) h[k] = (float)(red[0] / (double)PADN);
}

// ---------------------------------------------------------------------------
// Kernel 3: angle tables. ANGLES[a] = 2pi*a/NA + pi/2, computed in double.
// ---------------------------------------------------------------------------
__global__ void trig_kernel(float* __restrict__ cs, float* __restrict__ sn) {
    int a = blockIdx.x * 256 + threadIdx.x;
    if (a < NAANG) {
        double ang = 2.0 * M_PI * (double)a / (double)NAANG + M_PI / 2.0;
        cs[a] = (float)cos(ang);
        sn[a] = (float)sin(ang);
    }
}

// ---------------------------------------------------------------------------
// Kernel 4: per-row circular convolution with h (the FFT filter, exactly).
// filtered[row][i] = scale * sum_j sino[row][j] * h[(i-j) mod 2048]
// One block per row; each thread owns outputs i = t, t+256, t+512.
// LDS: h (8 KB) + row (2.9 KB). Consecutive t -> consecutive h index:
// stride-1, conflict-free; srow[j] is a broadcast.
// ---------------------------------------------------------------------------
__global__ void conv_kernel(const float* __restrict__ x,
                            const float* __restrict__ h,
                            float* __restrict__ fs) {
    __shared__ float sh[PADN];
    __shared__ float srow[NDET];
    const int row = blockIdx.x;
    const int t = threadIdx.x;
    for (int i = t; i < PADN; i += 256) sh[i] = h[i];
    for (int i = t; i < NDET; i += 256) srow[i] = x[row * NDET + i];
    __syncthreads();
    float a0 = 0.f, a1 = 0.f, a2 = 0.f;
    const int i0 = t, i1 = t + 256, i2 = t + 512;
    #pragma unroll 4
    for (int j = 0; j < NDET; ++j) {
        float rj = srow[j];
        a0 = fmaf(rj, sh[(i0 - j + PADN) & (PADN - 1)], a0);
        a1 = fmaf(rj, sh[(i1 - j + PADN) & (PADN - 1)], a1);
        a2 = fmaf(rj, sh[(i2 - j + PADN) & (PADN - 1)], a2);
    }
    const float scale = (float)(M_PI / (2.0 * (double)NAANG));
    fs[row * NDET + i0] = a0 * scale;
    fs[row * NDET + i1] = a1 * scale;
    if (i2 < NDET) fs[row * NDET + i2] = a2 * scale;
}

// ---------------------------------------------------------------------------
// Kernel 5: pixel-driven fan-beam backprojection + HU window.
// One thread per pixel; loops all 1152 angles; cos/sin staged in LDS.
// den = D - pdot is always > 0 (|pdot| <= 255.5*sqrt(2) < 850), so the
// reference's den>0 check is vacuous and omitted.
// ---------------------------------------------------------------------------
__global__ void backproj_kernel(const float* __restrict__ fs,
                                const float* __restrict__ cs,
                                const float* __restrict__ sn,
                                float* __restrict__ out) {
    __shared__ float sc[NAANG];
    __shared__ float ss[NAANG];
    const int t = threadIdx.x;
    for (int i = t; i < NAANG; i += 256) { sc[i] = cs[i]; ss[i] = sn[i]; }
    __syncthreads();

    const int ix = blockIdx.x * 256 + t;
    const int iy = blockIdx.y;
    const float xs = (float)ix - 255.5f;
    const float ys = (float)iy - 255.5f;
    const float Dg = 850.0f;                       // 595/0.7 exactly
    const float K  = (float)(1085.6 / 1.2858);     // DSD/DU (vox scaling cancels)

    float acc = 0.0f;
    for (int a = 0; a < NAANG; ++a) {
        float cb = sc[a];
        float sb = ss[a];
        float pdot = xs * cb + ys * sb;
        float pe   = ys * cb - xs * sb;
        float den  = Dg - pdot;
        float r    = 1.0f / den;
        float iu   = fmaf(K * pe, r, 367.5f);      // (ND-1)/2 = 367.5
        float i0f  = floorf(iu);
        float frac = iu - i0f;
        int   i0   = (int)i0f;
        bool  valid = (i0 >= 0) && (i0 < NDET - 1);
        int   ic   = min(max(i0, 0), NDET - 2);
        const float* rowp = fs + a * NDET;
        float v0 = rowp[ic];
        float v1 = rowp[ic + 1];
        float v  = fmaf(frac, v1 - v0, v0);        // linear interp
        float dr = Dg * r;
        float w  = dr * dr;                        // fan-beam weight
        acc += valid ? (w * v) : 0.0f;
    }
    // (1000*((fbp-0.0192)/0.0192) + 1024) / 4096 == fbp*12.7156575... + 24/4096
    out[iy * NPIX + ix] = fmaf(acc, (float)(1000.0 / 0.0192 / 4096.0), 0.005859375f);
}

extern "C" void kernel_launch(void* const* d_in, const int* in_sizes, int n_in,
                              void* d_out, int out_size, void* d_ws, size_t ws_size,
                              hipStream_t stream) {
    const float* x = (const float*)d_in[0];     // (1,1,1152,736) fp32 sinogram
    float* out = (float*)d_out;                 // (1,1,512,512) fp32

    char* ws = (char*)d_ws;
    double* filt_d = (double*)(ws + OFF_FILTD);
    float*  h      = (float*)(ws + OFF_H);
    float*  cs     = (float*)(ws + OFF_COS);
    float*  sn     = (float*)(ws + OFF_SIN);
    float*  fs     = (float*)(ws + OFF_FS);

    filt_spec_kernel<<<NHALF, 256, 0, stream>>>(filt_d);
    h_kernel<<<PADN, 256, 0, stream>>>(filt_d, h);
    trig_kernel<<<(NAANG + 255) / 256, 256, 0, stream>>>(cs, sn);
    conv_kernel<<<NAANG, 256, 0, stream>>>(x, h, fs);
    backproj_kernel<<<dim3(NPIX / 256, NPIX), 256, 0, stream>>>(fs, cs, sn, out);
}

// Round 2
// 268.624 us; speedup vs baseline: 1.4916x; 1.4916x over previous
//
#include <hip/hip_runtime.h>
#include <math.h>

#ifndef M_PI
#define M_PI 3.14159265358979323846
#endif

#define NAANG 1152
#define NDET  736
#define NPIX  512
#define PADN  2048
#define NHALF 1025   // PADN/2 + 1
#define CHUNK 2      // angle split for backprojection occupancy
#define AC    (NAANG / CHUNK)

// ---- workspace layout (byte offsets) ----
// double FILT[1025]            @ 0        (8200 B, pad to 8320)
// float  h[2048]               @ 8320     (8192 B)   [scale pre-folded]
// float2 trig[1152]            @ 16512    (9216 B)
// float  filtered[1152*736]    @ 25728    (3391488 B)
// float  partial[2*512*512]    @ 3417216  (2097152 B)
// total ~5.26 MB
#define OFF_FILTD 0
#define OFF_H     8320
#define OFF_TRIG  16512
#define OFF_FS    25728
#define OFF_PART  3417216

// ---------------------------------------------------------------------------
// Kernel 1: FILT[m] = Shepp-Logan half-spectrum (double precision).
// ---------------------------------------------------------------------------
__global__ void filt_spec_kernel(double* __restrict__ filt_d) {
    __shared__ double red[256];
    const int m = blockIdx.x;          // 0..1024
    const int t = threadIdx.x;
    double s = 0.0;
    for (int j = t; j < 1024; j += 256) {
        int n = (j < 512) ? (2 * j + 1) : (2047 - 2 * j);
        double fj = -1.0 / ((M_PI * n) * (M_PI * n));
        double ang = (2.0 * M_PI) * (double)m * (double)(2 * j + 1) / (double)PADN;
        s += fj * cos(ang);
    }
    red[t] = s;
    __syncthreads();
    for (int w = 128; w > 0; w >>= 1) {
        if (t < w) red[t] += red[t + w];
        __syncthreads();
    }
    if (t == 0) {
        double four = 2.0 * (0.25 + red[0]);
        if (m > 0) {
            double om = M_PI * (double)m / (double)PADN;
            four *= sin(om) / om;
        }
        filt_d[m] = four;
    }
}

// ---------------------------------------------------------------------------
// Kernel 2: h[k] = irfft(FILT, 2048)[k] * (pi / (2*NA))   (double precision).
// ---------------------------------------------------------------------------
__global__ void h_kernel(const double* __restrict__ filt_d, float* __restrict__ h) {
    __shared__ double red[256];
    const int k = blockIdx.x;          // 0..2047
    const int t = threadIdx.x;
    double s = 0.0;
    for (int m = t; m <= 1024; m += 256) {
        double c;
        if (m == 0) c = 1.0;
        else if (m == 1024) c = (k & 1) ? -1.0 : 1.0;
        else c = 2.0 * cos((2.0 * M_PI) * (double)m * (double)k / (double)PADN);
        s += filt_d[m] * c;
    }
    red[t] = s;
    __syncthreads();
    for (int w = 128; w > 0; w >>= 1) {
        if (t < w) red[t] += red[t + w];
        __syncthreads();
    }
    if (t == 0)
        h[k] = (float)(red[0] / (double)PADN * (M_PI / (2.0 * (double)NAANG)));
}

// ---------------------------------------------------------------------------
// Kernel 3: interleaved angle table: trig[a] = (cos, sin), double-computed.
// ---------------------------------------------------------------------------
__global__ void trig_kernel(float2* __restrict__ trig) {
    int a = blockIdx.x * 256 + threadIdx.x;
    if (a < NAANG) {
        double ang = 2.0 * M_PI * (double)a / (double)NAANG + M_PI / 2.0;
        trig[a] = make_float2((float)cos(ang), (float)sin(ang));
    }
}

// ---------------------------------------------------------------------------
// Kernel 4: per-row circular convolution with h (exactly the FFT filter).
// h duplicated into sh2[2816] so indices i - j + 2048 ∈ [1313, 2815] need no
// mask; 3 outputs/thread at +0/+256/+512 -> immediate-offset ds_reads off one
// base register; taps read 4-at-a-time via ds_read_b128 broadcast.
// ---------------------------------------------------------------------------
__global__ void conv_kernel(const float* __restrict__ x,
                            const float* __restrict__ h,
                            float* __restrict__ fs) {
    __shared__ float sh2[2816];
    __shared__ float srow[NDET];
    const int row = blockIdx.x;
    const int t = threadIdx.x;
    for (int i = t; i < 2816; i += 256) sh2[i] = h[i & (PADN - 1)];
    const float4* x4 = (const float4*)(x + row * NDET);
    for (int i = t; i < NDET / 4; i += 256) ((float4*)srow)[i] = x4[i];
    __syncthreads();

    float a0 = 0.f, a1 = 0.f, a2 = 0.f;
    const int base = t + PADN;               // 2048 + i0
    #pragma unroll 2
    for (int j = 0; j < NDET; j += 4) {
        float4 r4 = *(const float4*)&srow[j];
        const float* p = &sh2[base - j];
        a0 = fmaf(r4.x, p[0],   a0); a1 = fmaf(r4.x, p[256], a1); a2 = fmaf(r4.x, p[512], a2);
        a0 = fmaf(r4.y, p[-1],  a0); a1 = fmaf(r4.y, p[255], a1); a2 = fmaf(r4.y, p[511], a2);
        a0 = fmaf(r4.z, p[-2],  a0); a1 = fmaf(r4.z, p[254], a1); a2 = fmaf(r4.z, p[510], a2);
        a0 = fmaf(r4.w, p[-3],  a0); a1 = fmaf(r4.w, p[253], a1); a2 = fmaf(r4.w, p[509], a2);
    }
    fs[row * NDET + t] = a0;
    fs[row * NDET + t + 256] = a1;
    if (t + 512 < NDET) fs[row * NDET + t + 512] = a2;
}

// ---------------------------------------------------------------------------
// Kernel 5: fan-beam backprojection, angle chunk z of CHUNK.
// grid (2, 512, CHUNK) = 2048 blocks -> 8 blocks/CU -> 32 waves/CU (100%).
// Fast rcp (1 ulp), single unsigned validity compare, med3 clamp.
// den = D - pdot > 0 always (|pdot| <= 361 < 850) so den>0 check omitted.
// ---------------------------------------------------------------------------
__global__ void backproj_kernel(const float* __restrict__ fs,
                                const float2* __restrict__ trig,
                                float* __restrict__ partial) {
    __shared__ float2 st[AC];
    const int t = threadIdx.x;
    const int zc = blockIdx.z;
    const int abase = zc * AC;
    for (int i = t; i < AC; i += 256) st[i] = trig[abase + i];
    __syncthreads();

    const int ix = blockIdx.x * 256 + t;
    const int iy = blockIdx.y;
    const float xs = (float)ix - 255.5f;
    const float ys = (float)iy - 255.5f;
    const float Dg = 850.0f;                    // 595/0.7 exactly
    const float K  = (float)(1085.6 / 1.2858);  // DSD/DU (vox scaling cancels)

    const float* rowp = fs + abase * NDET;
    float acc = 0.0f;
    for (int a = 0; a < AC; ++a, rowp += NDET) {
        float2 cs2 = st[a];
        float cb = cs2.x, sb = cs2.y;
        float pdot = fmaf(xs, cb, ys * sb);
        float pe   = fmaf(ys, cb, -(xs * sb));
        float den  = Dg - pdot;
        float r    = __builtin_amdgcn_rcpf(den);     // v_rcp_f32, ~1 ulp
        float iu   = fmaf(K * pe, r, 367.5f);        // (ND-1)/2 = 367.5
        float i0f  = floorf(iu);
        float frac = iu - i0f;
        int   i0   = (int)i0f;
        int   ic   = min(max(i0, 0), NDET - 2);      // v_med3_i32
        float v0 = rowp[ic];
        float v1 = rowp[ic + 1];
        float v  = fmaf(frac, v1 - v0, v0);
        float dr = Dg * r;
        float w  = dr * dr;
        w = ((unsigned)i0 < (unsigned)(NDET - 1)) ? w : 0.0f;
        acc = fmaf(w, v, acc);
    }
    partial[zc * NPIX * NPIX + iy * NPIX + ix] = acc;
}

// ---------------------------------------------------------------------------
// Kernel 6: sum partials + HU window.
// ---------------------------------------------------------------------------
__global__ void combine_kernel(const float* __restrict__ partial,
                               float* __restrict__ out) {
    int p = blockIdx.x * 256 + threadIdx.x;
    float s = partial[p] + partial[NPIX * NPIX + p];
    // (1000*((fbp-0.0192)/0.0192) + 1024) / 4096 == fbp*(1000/0.0192/4096) + 24/4096
    out[p] = fmaf(s, (float)(1000.0 / 0.0192 / 4096.0), 0.005859375f);
}

extern "C" void kernel_launch(void* const* d_in, const int* in_sizes, int n_in,
                              void* d_out, int out_size, void* d_ws, size_t ws_size,
                              hipStream_t stream) {
    const float* x = (const float*)d_in[0];     // (1,1,1152,736) fp32 sinogram
    float* out = (float*)d_out;                 // (1,1,512,512) fp32

    char* ws = (char*)d_ws;
    double* filt_d = (double*)(ws + OFF_FILTD);
    float*  h      = (float*)(ws + OFF_H);
    float2* trig   = (float2*)(ws + OFF_TRIG);
    float*  fs     = (float*)(ws + OFF_FS);
    float*  part   = (float*)(ws + OFF_PART);

    filt_spec_kernel<<<NHALF, 256, 0, stream>>>(filt_d);
    h_kernel<<<PADN, 256, 0, stream>>>(filt_d, h);
    trig_kernel<<<(NAANG + 255) / 256, 256, 0, stream>>>(trig);
    conv_kernel<<<NAANG, 256, 0, stream>>>(x, h, fs);
    backproj_kernel<<<dim3(NPIX / 256, NPIX, CHUNK), 256, 0, stream>>>(fs, trig, part);
    combine_kernel<<<NPIX * NPIX / 256, 256, 0, stream>>>(part, out);
}

// Round 3
// 266.752 us; speedup vs baseline: 1.5020x; 1.0070x over previous
//
#include <hip/hip_runtime.h>
#include <math.h>

#ifndef M_PI
#define M_PI 3.14159265358979323846
#endif

#define NAANG 1152
#define NDET  736
#define NPIX  512
#define PADN  2048
#define NHALF 1025   // PADN/2 + 1

// ---- workspace layout (byte offsets) ----
// double FILT[1025]            @ 0        (8200 B, pad 8320)
// float  h[2048]               @ 8320     (8192 B)   [pi/(2NA) scale folded]
// float4 trig[1152]            @ 16512    (18432 B)  (cb, sb, K*cb, K*sb)
// float  filtered[1152*736]    @ 34944    (3391488 B)
// float  partial[NCH*512*512]  @ 3426432  (NCH MiB)
#define OFF_FILTD 0
#define OFF_H     8320
#define OFF_TRIG  16512
#define OFF_FS    34944
#define OFF_PART  3426432

// ---------------------------------------------------------------------------
// Kernel 1: FILT[m] = Shepp-Logan half-spectrum (double precision).
// ---------------------------------------------------------------------------
__global__ void filt_spec_kernel(double* __restrict__ filt_d) {
    __shared__ double red[256];
    const int m = blockIdx.x;          // 0..1024
    const int t = threadIdx.x;
    double s = 0.0;
    for (int j = t; j < 1024; j += 256) {
        int n = (j < 512) ? (2 * j + 1) : (2047 - 2 * j);
        double fj = -1.0 / ((M_PI * n) * (M_PI * n));
        double ang = (2.0 * M_PI) * (double)m * (double)(2 * j + 1) / (double)PADN;
        s += fj * cos(ang);
    }
    red[t] = s;
    __syncthreads();
    for (int w = 128; w > 0; w >>= 1) {
        if (t < w) red[t] += red[t + w];
        __syncthreads();
    }
    if (t == 0) {
        double four = 2.0 * (0.25 + red[0]);
        if (m > 0) {
            double om = M_PI * (double)m / (double)PADN;
            four *= sin(om) / om;
        }
        filt_d[m] = four;
    }
}

// ---------------------------------------------------------------------------
// Kernel 2: h[k] = irfft(FILT,2048)[k] * pi/(2*NA); block k<1152 lane 0 also
// fills the trig table (fused to save a launch).
// ---------------------------------------------------------------------------
__global__ void h_kernel(const double* __restrict__ filt_d, float* __restrict__ h,
                         float4* __restrict__ trig) {
    __shared__ double red[256];
    const int k = blockIdx.x;          // 0..2047
    const int t = threadIdx.x;
    if (t == 0 && k < NAANG) {
        double ang = 2.0 * M_PI * (double)k / (double)NAANG + M_PI / 2.0;
        double c = cos(ang), s = sin(ang);
        double K = 1085.6 / 1.2858;    // DSD/DU (vox scaling cancels)
        trig[k] = make_float4((float)c, (float)s, (float)(K * c), (float)(K * s));
    }
    double s = 0.0;
    for (int m = t; m <= 1024; m += 256) {
        double c;
        if (m == 0) c = 1.0;
        else if (m == 1024) c = (k & 1) ? -1.0 : 1.0;
        else c = 2.0 * cos((2.0 * M_PI) * (double)m * (double)k / (double)PADN);
        s += filt_d[m] * c;
    }
    red[t] = s;
    __syncthreads();
    for (int w = 128; w > 0; w >>= 1) {
        if (t < w) red[t] += red[t + w];
        __syncthreads();
    }
    if (t == 0)
        h[k] = (float)(red[0] / (double)PADN * (M_PI / (2.0 * (double)NAANG)));
}

// ---------------------------------------------------------------------------
// Kernel 3: circular convolution, aligned-b128 form. Block = 192 threads,
// one row; lane t produces outputs i = 4t..4t+3 (t<184). Per 4-tap group:
// 2 aligned ds_read_b128 (lane window) + 1 broadcast b128 (taps) + 16 fma.
// ---------------------------------------------------------------------------
__global__ void conv_kernel(const float* __restrict__ x,
                            const float* __restrict__ h,
                            float* __restrict__ fs) {
    __shared__ float sh2[2816];        // h duplicated: sh2[i] = h[i & 2047]
    __shared__ float srow[NDET];
    const int row = blockIdx.x;
    const int t = threadIdx.x;
    const float4* h4 = (const float4*)h;
    for (int i = t; i < 704; i += 192) ((float4*)sh2)[i] = h4[i & 511];
    const float4* x4 = (const float4*)(x + row * NDET);
    for (int i = t; i < NDET / 4; i += 192) ((float4*)srow)[i] = x4[i];
    __syncthreads();

    const int t4 = 4 * t;
    float o0 = 0.f, o1 = 0.f, o2 = 0.f, o3 = 0.f;
    #pragma unroll 2
    for (int j = 0; j < NDET; j += 4) {
        float4 r4 = *(const float4*)&srow[j];
        const int A = t4 + PADN - j;
        float4 hlo = *(const float4*)&sh2[A - 4];   // sh2[A-4..A-1]
        float4 hhi = *(const float4*)&sh2[A];       // sh2[A..A+3]
        o0 = fmaf(r4.x, hhi.x, o0); o0 = fmaf(r4.y, hlo.w, o0);
        o0 = fmaf(r4.z, hlo.z, o0); o0 = fmaf(r4.w, hlo.y, o0);
        o1 = fmaf(r4.x, hhi.y, o1); o1 = fmaf(r4.y, hhi.x, o1);
        o1 = fmaf(r4.z, hlo.w, o1); o1 = fmaf(r4.w, hlo.z, o1);
        o2 = fmaf(r4.x, hhi.z, o2); o2 = fmaf(r4.y, hhi.y, o2);
        o2 = fmaf(r4.z, hhi.x, o2); o2 = fmaf(r4.w, hlo.w, o2);
        o3 = fmaf(r4.x, hhi.w, o3); o3 = fmaf(r4.y, hhi.z, o3);
        o3 = fmaf(r4.z, hhi.y, o3); o3 = fmaf(r4.w, hhi.x, o3);
    }
    if (t < NDET / 4)
        *(float4*)&fs[row * NDET + t4] = make_float4(o0, o1, o2, o3);
}

// ---------------------------------------------------------------------------
// Kernel 4: fan-beam backprojection. 2 pixels/thread (adjacent y):
// den1 = den0 - sb, kpe1 = kpe0 + K*cb (2 ops for the 2nd pixel's geometry),
// two independent chains for latency hiding. grid (2, 256, NCH).
// ---------------------------------------------------------------------------
template<int NCH>
__global__ __launch_bounds__(256, 8)
void backproj_kernel(const float* __restrict__ fs,
                     const float4* __restrict__ trig,
                     float* __restrict__ partial) {
    constexpr int ACL = NAANG / NCH;
    __shared__ float4 st[ACL];
    const int t = threadIdx.x;
    const int abase = blockIdx.z * ACL;
    for (int i = t; i < ACL; i += 256) st[i] = trig[abase + i];
    __syncthreads();

    const int ix = blockIdx.x * 256 + t;
    const int iy = blockIdx.y * 2;
    const float xs  = (float)ix - 255.5f;
    const float ys0 = (float)iy - 255.5f;
    const float Dg = 850.0f;                  // 595/0.7 exactly

    const float* rowp = fs + abase * NDET;
    float acc0 = 0.f, acc1 = 0.f;
    for (int a = 0; a < ACL; ++a, rowp += NDET) {
        float4 q = st[a];                     // cb, sb, K*cb, K*sb
        float den0 = fmaf(-xs, q.x, fmaf(-ys0, q.y, Dg));
        float kpe0 = fmaf(ys0, q.z, -(xs * q.w));
        float den1 = den0 - q.y;
        float kpe1 = kpe0 + q.z;
        float r0 = __builtin_amdgcn_rcpf(den0);
        float r1 = __builtin_amdgcn_rcpf(den1);
        float iu0 = fmaf(kpe0, r0, 367.5f);   // (ND-1)/2
        float iu1 = fmaf(kpe1, r1, 367.5f);
        float f0 = floorf(iu0), f1 = floorf(iu1);
        int   i0 = (int)f0,     i1 = (int)f1;
        int   c0 = min(max(i0, 0), NDET - 2);
        int   c1 = min(max(i1, 0), NDET - 2);
        float fr0 = iu0 - f0,   fr1 = iu1 - f1;
        float a0 = rowp[c0], b0 = rowp[c0 + 1];
        float a1 = rowp[c1], b1 = rowp[c1 + 1];
        float v0 = fmaf(fr0, b0 - a0, a0);
        float v1 = fmaf(fr1, b1 - a1, a1);
        float d0 = Dg * r0, d1 = Dg * r1;
        float w0 = d0 * d0, w1 = d1 * d1;
        w0 = ((unsigned)i0 < (unsigned)(NDET - 1)) ? w0 : 0.f;
        w1 = ((unsigned)i1 < (unsigned)(NDET - 1)) ? w1 : 0.f;
        acc0 = fmaf(w0, v0, acc0);
        acc1 = fmaf(w1, v1, acc1);
    }
    partial[(blockIdx.z * NPIX + iy) * NPIX + ix] = acc0;
    partial[(blockIdx.z * NPIX + iy + 1) * NPIX + ix] = acc1;
}

// ---------------------------------------------------------------------------
// Kernel 5: sum partials + HU window.
// ---------------------------------------------------------------------------
template<int NCH>
__global__ void combine_kernel(const float* __restrict__ partial,
                               float* __restrict__ out) {
    int p = blockIdx.x * 256 + threadIdx.x;
    float s = 0.f;
    #pragma unroll
    for (int c = 0; c < NCH; ++c) s += partial[c * NPIX * NPIX + p];
    // (1000*((fbp-0.0192)/0.0192)+1024)/4096 = fbp*(1000/0.0192/4096) + 24/4096
    out[p] = fmaf(s, (float)(1000.0 / 0.0192 / 4096.0), 0.005859375f);
}

extern "C" void kernel_launch(void* const* d_in, const int* in_sizes, int n_in,
                              void* d_out, int out_size, void* d_ws, size_t ws_size,
                              hipStream_t stream) {
    const float* x = (const float*)d_in[0];     // (1,1,1152,736) fp32 sinogram
    float* out = (float*)d_out;                 // (1,1,512,512) fp32

    char* ws = (char*)d_ws;
    double* filt_d = (double*)(ws + OFF_FILTD);
    float*  h      = (float*)(ws + OFF_H);
    float4* trig   = (float4*)(ws + OFF_TRIG);
    float*  fs     = (float*)(ws + OFF_FS);
    float*  part   = (float*)(ws + OFF_PART);

    filt_spec_kernel<<<NHALF, 256, 0, stream>>>(filt_d);
    h_kernel<<<PADN, 256, 0, stream>>>(filt_d, h, trig);
    conv_kernel<<<NAANG, 192, 0, stream>>>(x, h, fs);

    const size_t pbytes = (size_t)NPIX * NPIX * 4;
    if (ws_size >= OFF_PART + 4 * pbytes) {
        backproj_kernel<4><<<dim3(2, 256, 4), 256, 0, stream>>>(fs, trig, part);
        combine_kernel<4><<<NPIX * NPIX / 256, 256, 0, stream>>>(part, out);
    } else if (ws_size >= OFF_PART + 2 * pbytes) {
        backproj_kernel<2><<<dim3(2, 256, 2), 256, 0, stream>>>(fs, trig, part);
        combine_kernel<2><<<NPIX * NPIX / 256, 256, 0, stream>>>(part, out);
    } else {
        backproj_kernel<1><<<dim3(2, 256, 1), 256, 0, stream>>>(fs, trig, part);
        combine_kernel<1><<<NPIX * NPIX / 256, 256, 0, stream>>>(part, out);
    }
}